// Round 1
// baseline (8233.134 us; speedup 1.0000x reference)
//
#include <hip/hip_runtime.h>
#include <cstdint>

// ---- problem constants (reference file) ----
constexpr int N_   = 2048;   // sequence length (B=1)
constexpr int D_   = 1024;   // model dim
constexpr int H_   = 16;     // heads
constexpr int DH_  = 64;     // head dim
constexpr int TRI  = 3072;   // 3*INNER
constexpr int FF_  = 4096;
constexpr int V_   = 50257;

__device__ __forceinline__ float gelu_exact(float x) {
    return 0.5f * x * (1.0f + erff(x * 0.70710678118654752f));
}

// ---------------- embedding: h = tok_emb[x] + pos_emb ----------------
__global__ __launch_bounds__(256) void embed_kernel(
    const int* __restrict__ x, const float* __restrict__ tok,
    const float* __restrict__ pos, float* __restrict__ h)
{
    const int n = blockIdx.x;
    const int t = threadIdx.x;
    const int id = x[n];
    float4 a = *(const float4*)(tok + (size_t)id * D_ + t * 4);
    float4 p = *(const float4*)(pos + (size_t)n * D_ + t * 4);
    float4 o;
    o.x = a.x + p.x; o.y = a.y + p.y; o.z = a.z + p.z; o.w = a.w + p.w;
    *(float4*)(h + (size_t)n * D_ + t * 4) = o;
}

// ---------------- layernorm (row per block, D=1024, 256 thr x float4) ---
__global__ __launch_bounds__(256) void ln_kernel(
    const float* __restrict__ x, const float* __restrict__ g,
    const float* __restrict__ b, float* __restrict__ y)
{
    __shared__ float sm[8];
    const int row = blockIdx.x;
    const int t = threadIdx.x;
    const int lane = t & 63, w = t >> 6;
    float4 v = *(const float4*)(x + (size_t)row * D_ + t * 4);
    float s = v.x + v.y + v.z + v.w;
    #pragma unroll
    for (int off = 32; off > 0; off >>= 1) s += __shfl_down(s, off);
    if (lane == 0) sm[w] = s;
    __syncthreads();
    const float mu = (sm[0] + sm[1] + sm[2] + sm[3]) * (1.0f / D_);
    float4 d;
    d.x = v.x - mu; d.y = v.y - mu; d.z = v.z - mu; d.w = v.w - mu;
    float s2 = d.x*d.x + d.y*d.y + d.z*d.z + d.w*d.w;
    #pragma unroll
    for (int off = 32; off > 0; off >>= 1) s2 += __shfl_down(s2, off);
    if (lane == 0) sm[4 + w] = s2;
    __syncthreads();
    const float var = (sm[4] + sm[5] + sm[6] + sm[7]) * (1.0f / D_);
    const float rstd = rsqrtf(var + 1e-5f);
    float4 gv = *(const float4*)(g + t * 4);
    float4 bv = *(const float4*)(b + t * 4);
    float4 o;
    o.x = d.x * rstd * gv.x + bv.x;
    o.y = d.y * rstd * gv.y + bv.y;
    o.z = d.z * rstd * gv.z + bv.z;
    o.w = d.w * rstd * gv.w + bv.w;
    *(float4*)(y + (size_t)row * D_ + t * 4) = o;
}

// ---------------- fp32 tiled GEMM -------------------------------------
// C[M,Np] = A[M,K] @ B  (+bias +gelu +res per flags)
// NT=false: B is [K,Np] row-major.  NT=true: B is [Np,K] row-major (dot over K).
// 128x128 tile, BK=16, 256 threads, 8x8 per thread.
// LDS k-major: compute reads are b128 broadcast (A, 4 distinct banks) and
// b32 stride-1 across tx (B, interleaved col map) -> <=2-way aliasing.
template<bool NT, bool BIAS, bool RES, bool GELU_ACT>
__global__ __launch_bounds__(256) void gemm_kernel(
    const float* __restrict__ A, const float* __restrict__ B,
    const float* __restrict__ bias, const float* res,
    float* C, int M, int Np, int K)
{
    constexpr int BM = 128, BN = 128, BK = 16;
    __shared__ float As[BK][BM];   // [k][m]
    __shared__ float Bs[BK][BN];   // [k][n]
    const int t  = threadIdx.x;
    const int tx = t & 15, ty = t >> 4;
    const int bm = blockIdx.y * BM;
    const int bn = blockIdx.x * BN;

    float acc[8][8];
    #pragma unroll
    for (int r = 0; r < 8; ++r)
        #pragma unroll
        for (int c = 0; c < 8; ++c) acc[r][c] = 0.0f;

    for (int kt = 0; kt < K; kt += BK) {
        __syncthreads();   // protect LDS from previous iter's reads
        // A tile: 128x16 = 512 float4, transpose-store to [k][m]
        #pragma unroll
        for (int j = 0; j < 2; ++j) {
            int i = t + j * 256;
            int row = i >> 2;
            int k0 = (i & 3) << 2;
            float4 av = *(const float4*)(A + (size_t)(bm + row) * K + kt + k0);
            As[k0 + 0][row] = av.x; As[k0 + 1][row] = av.y;
            As[k0 + 2][row] = av.z; As[k0 + 3][row] = av.w;
        }
        if (!NT) {
            // B tile: 16x128, direct b128 store
            #pragma unroll
            for (int j = 0; j < 2; ++j) {
                int i = t + j * 256;
                int row = i >> 5;
                int c0 = (i & 31) << 2;
                *(float4*)&Bs[row][c0] =
                    *(const float4*)(B + (size_t)(kt + row) * Np + bn + c0);
            }
        } else {
            // B rows are output cols: gather + transpose, guard col < Np
            #pragma unroll
            for (int j = 0; j < 2; ++j) {
                int i = t + j * 256;
                int c = i >> 2;
                int k0 = (i & 3) << 2;
                float4 bv = make_float4(0.f, 0.f, 0.f, 0.f);
                if (bn + c < Np)
                    bv = *(const float4*)(B + (size_t)(bn + c) * K + kt + k0);
                Bs[k0 + 0][c] = bv.x; Bs[k0 + 1][c] = bv.y;
                Bs[k0 + 2][c] = bv.z; Bs[k0 + 3][c] = bv.w;
            }
        }
        __syncthreads();
        #pragma unroll
        for (int k = 0; k < BK; ++k) {
            float a[8], bb[8];
            *(float4*)&a[0] = *(const float4*)&As[k][ty * 8];
            *(float4*)&a[4] = *(const float4*)&As[k][ty * 8 + 4];
            #pragma unroll
            for (int cc = 0; cc < 4; ++cc) {
                bb[cc]     = Bs[k][cc * 16 + tx];        // cols interleaved:
                bb[4 + cc] = Bs[k][64 + cc * 16 + tx];   // tx+16*cc (+64)
            }
            #pragma unroll
            for (int r = 0; r < 8; ++r)
                #pragma unroll
                for (int c = 0; c < 8; ++c)
                    acc[r][c] = fmaf(a[r], bb[c], acc[r][c]);
        }
    }
    // epilogue: scalar stores, perfectly coalesced across tx (stride 1)
    #pragma unroll
    for (int r = 0; r < 8; ++r) {
        const int grow = bm + ty * 8 + r;
        const size_t roff = (size_t)grow * Np;
        #pragma unroll
        for (int half = 0; half < 2; ++half)
            #pragma unroll
            for (int cc = 0; cc < 4; ++cc) {
                const int gcol = bn + half * 64 + cc * 16 + tx;
                if (NT && gcol >= Np) continue;
                float v = acc[r][half * 4 + cc];
                if (BIAS)     v += bias[gcol];
                if (GELU_ACT) v = gelu_exact(v);
                if (RES)      v += res[roff + gcol];
                C[roff + gcol] = v;
            }
    }
}

// ---------------- flash attention (fp32, causal) ----------------------
// Block = (64 q-rows, one head). Iterate 32-wide key blocks with online
// softmax. 256 threads: tx=t&15 (16), ty=t>>4 (16); thread owns 4 q-rows
// (ty*4+r), 2 key-cols (tx*2+c) for S, 4 dh-cols (tx*4+c) for O.
__global__ __launch_bounds__(256) void attn_kernel(const float* __restrict__ qkv,
                                                   float* __restrict__ att)
{
    constexpr int AKB = 32;
    const int hh = blockIdx.y;
    const int qb = blockIdx.x;
    const int q0 = qb * 64;
    const int t  = threadIdx.x;
    const int tx = t & 15, ty = t >> 4;

    __shared__ float Qs[64][65];       // [d][qrow]  (pad: transpose writes 2-way)
    __shared__ float Ks[64][AKB + 1];  // [d][kcol]
    __shared__ float Vs[AKB][64];      // [krow][d]
    __shared__ float Ps[64][AKB + 1];  // [qrow][kcol]

    // stage Q transposed (once)
    #pragma unroll
    for (int j = 0; j < 4; ++j) {
        int i = t + j * 256;
        int row = i >> 4;
        int d0 = (i & 15) << 2;
        float4 qv = *(const float4*)(qkv + (size_t)(q0 + row) * TRI + hh * DH_ + d0);
        Qs[d0+0][row] = qv.x; Qs[d0+1][row] = qv.y;
        Qs[d0+2][row] = qv.z; Qs[d0+3][row] = qv.w;
    }

    float m[4], l[4], o[4][4];
    #pragma unroll
    for (int r = 0; r < 4; ++r) {
        m[r] = -3.0e38f; l[r] = 0.0f;
        #pragma unroll
        for (int c = 0; c < 4; ++c) o[r][c] = 0.0f;
    }

    const int nkb = 2 * (qb + 1);            // causal: keys up to q0+63
    for (int kb = 0; kb < nkb; ++kb) {
        const int k0 = kb * AKB;
        __syncthreads();                     // prev PV reads done / Q staged
        #pragma unroll
        for (int j = 0; j < 2; ++j) {
            int i = t + j * 256;
            int col = i >> 4;
            int d0 = (i & 15) << 2;
            float4 kv = *(const float4*)(qkv + (size_t)(k0 + col) * TRI + 1024 + hh * DH_ + d0);
            Ks[d0+0][col] = kv.x; Ks[d0+1][col] = kv.y;
            Ks[d0+2][col] = kv.z; Ks[d0+3][col] = kv.w;
            float4 vv = *(const float4*)(qkv + (size_t)(k0 + col) * TRI + 2048 + hh * DH_ + d0);
            *(float4*)&Vs[col][d0] = vv;
        }
        __syncthreads();

        // S = Q K^T  (4x2 per thread)
        float s[4][2];
        #pragma unroll
        for (int r = 0; r < 4; ++r) { s[r][0] = 0.f; s[r][1] = 0.f; }
        for (int d = 0; d < 64; ++d) {
            float qa[4];
            #pragma unroll
            for (int r = 0; r < 4; ++r) qa[r] = Qs[d][ty * 4 + r];
            float kv0 = Ks[d][tx * 2 + 0];
            float kv1 = Ks[d][tx * 2 + 1];
            #pragma unroll
            for (int r = 0; r < 4; ++r) {
                s[r][0] = fmaf(qa[r], kv0, s[r][0]);
                s[r][1] = fmaf(qa[r], kv1, s[r][1]);
            }
        }
        // scale + causal mask
        #pragma unroll
        for (int r = 0; r < 4; ++r) {
            const int qr = q0 + ty * 4 + r;
            #pragma unroll
            for (int c = 0; c < 2; ++c) {
                const int kc = k0 + tx * 2 + c;
                s[r][c] = (kc <= qr) ? s[r][c] * 0.125f : -1e30f;
            }
        }
        // online softmax (16-lane groups share a row)
        #pragma unroll
        for (int r = 0; r < 4; ++r) {
            float rmax = fmaxf(s[r][0], s[r][1]);
            #pragma unroll
            for (int off = 1; off < 16; off <<= 1)
                rmax = fmaxf(rmax, __shfl_xor(rmax, off, 16));
            const float mn = fmaxf(m[r], rmax);
            const float p0 = expf(s[r][0] - mn);
            const float p1 = expf(s[r][1] - mn);
            s[r][0] = p0; s[r][1] = p1;
            float rsum = p0 + p1;
            #pragma unroll
            for (int off = 1; off < 16; off <<= 1)
                rsum += __shfl_xor(rsum, off, 16);
            const float sc = expf(m[r] - mn);
            l[r] = l[r] * sc + rsum;
            m[r] = mn;
            #pragma unroll
            for (int c = 0; c < 4; ++c) o[r][c] *= sc;
        }
        // share P
        #pragma unroll
        for (int r = 0; r < 4; ++r) {
            Ps[ty * 4 + r][tx * 2 + 0] = s[r][0];
            Ps[ty * 4 + r][tx * 2 + 1] = s[r][1];
        }
        __syncthreads();
        // O += P V
        #pragma unroll 4
        for (int j = 0; j < AKB; ++j) {
            float pv[4];
            #pragma unroll
            for (int r = 0; r < 4; ++r) pv[r] = Ps[ty * 4 + r][j];
            float4 vv = *(const float4*)&Vs[j][tx * 4];
            #pragma unroll
            for (int r = 0; r < 4; ++r) {
                o[r][0] = fmaf(pv[r], vv.x, o[r][0]);
                o[r][1] = fmaf(pv[r], vv.y, o[r][1]);
                o[r][2] = fmaf(pv[r], vv.z, o[r][2]);
                o[r][3] = fmaf(pv[r], vv.w, o[r][3]);
            }
        }
    }
    // finalize: O / l, store [n, h*64+dh]
    #pragma unroll
    for (int r = 0; r < 4; ++r) {
        const float inv = 1.0f / l[r];
        float4 ov;
        ov.x = o[r][0]*inv; ov.y = o[r][1]*inv; ov.z = o[r][2]*inv; ov.w = o[r][3]*inv;
        *(float4*)(att + (size_t)(q0 + ty * 4 + r) * 1024 + hh * DH_ + tx * 4) = ov;
    }
}

// ---------------- launcher --------------------------------------------
extern "C" void kernel_launch(void* const* d_in, const int* in_sizes, int n_in,
                              void* d_out, int out_size, void* d_ws, size_t ws_size,
                              hipStream_t stream)
{
    (void)in_sizes; (void)n_in; (void)out_size; (void)ws_size;
    const int*   x    = (const int*)  d_in[0];
    const float* tok  = (const float*)d_in[1];
    const float* pos  = (const float*)d_in[2];
    const float* ln1g = (const float*)d_in[3];
    const float* ln1b = (const float*)d_in[4];
    const float* wqkv = (const float*)d_in[5];
    const float* wo   = (const float*)d_in[6];
    const float* bo   = (const float*)d_in[7];
    const float* ln2g = (const float*)d_in[8];
    const float* ln2b = (const float*)d_in[9];
    const float* w1   = (const float*)d_in[10];
    const float* b1   = (const float*)d_in[11];
    const float* w2   = (const float*)d_in[12];
    const float* b2   = (const float*)d_in[13];
    const float* lnfg = (const float*)d_in[14];
    const float* lnfb = (const float*)d_in[15];
    float* out = (float*)d_out;

    // workspace: h, y, qkv, att, ff  (~84 MB fp32)
    float* h   = (float*)d_ws;
    float* y   = h   + (size_t)N_ * D_;
    float* qkv = y   + (size_t)N_ * D_;
    float* att = qkv + (size_t)N_ * TRI;
    float* ff  = att + (size_t)N_ * D_;

    embed_kernel<<<N_, 256, 0, stream>>>(x, tok, pos, h);

    for (int l = 0; l < 2; ++l) {
        ln_kernel<<<N_, 256, 0, stream>>>(h, ln1g + l * D_, ln1b + l * D_, y);
        gemm_kernel<false,false,false,false><<<dim3(TRI / 128, N_ / 128), 256, 0, stream>>>(
            y, wqkv + (size_t)l * D_ * TRI, nullptr, nullptr, qkv, N_, TRI, D_);
        attn_kernel<<<dim3(N_ / 64, H_), 256, 0, stream>>>(qkv, att);
        gemm_kernel<false,true,true,false><<<dim3(D_ / 128, N_ / 128), 256, 0, stream>>>(
            att, wo + (size_t)l * D_ * D_, bo + l * D_, h, h, N_, D_, D_);
        ln_kernel<<<N_, 256, 0, stream>>>(h, ln2g + l * D_, ln2b + l * D_, y);
        gemm_kernel<false,true,false,true><<<dim3(FF_ / 128, N_ / 128), 256, 0, stream>>>(
            y, w1 + (size_t)l * D_ * FF_, b1 + l * FF_, nullptr, ff, N_, FF_, D_);
        gemm_kernel<false,true,true,false><<<dim3(D_ / 128, N_ / 128), 256, 0, stream>>>(
            ff, w2 + (size_t)l * FF_ * D_, b2 + l * D_, h, h, N_, D_, FF_);
    }
    ln_kernel<<<N_, 256, 0, stream>>>(h, lnfg, lnfb, y);
    // logits = y @ tok_emb^T  (NT GEMM, guard V=50257)
    gemm_kernel<true,false,false,false><<<dim3((V_ + 127) / 128, N_ / 128), 256, 0, stream>>>(
        y, tok, nullptr, nullptr, out, N_, V_, D_);
}

// Round 2
// 3475.351 us; speedup vs baseline: 2.3690x; 2.3690x over previous
//
#include <hip/hip_runtime.h>
#include <cstdint>

// ---- problem constants ----
constexpr int N_   = 2048;
constexpr int D_   = 1024;
constexpr int H_   = 16;
constexpr int DH_  = 64;
constexpr int TRI  = 3072;   // 3*INNER
constexpr int FF_  = 4096;
constexpr int V_   = 50257;
constexpr int VPAD = 50304;  // 393*128

using u16 = unsigned short;
typedef __bf16 bf16x8 __attribute__((ext_vector_type(8)));
typedef float  f32x4  __attribute__((ext_vector_type(4)));

__device__ __forceinline__ float gelu_exact(float x) {
    return 0.5f * x * (1.0f + erff(x * 0.70710678118654752f));
}
__device__ __forceinline__ u16 f2bf(float f) {
    uint32_t u = __float_as_uint(f);
    u += 0x7FFFu + ((u >> 16) & 1u);
    return (u16)(u >> 16);
}
__device__ __forceinline__ float bf2f(u16 s) {
    return __uint_as_float(((uint32_t)s) << 16);
}
__device__ __forceinline__ void split2(float x, u16& hi, u16& lo) {
    hi = f2bf(x);
    lo = f2bf(x - bf2f(hi));
}
// async global->LDS, 16B per lane (dest must be wave-linear: base + lane*16)
__device__ __forceinline__ void gl_lds16(const void* g, void* l) {
    __builtin_amdgcn_global_load_lds(
        (const __attribute__((address_space(1))) uint32_t*)g,
        (__attribute__((address_space(3))) uint32_t*)l, 16, 0, 0);
}

// ---------------- embedding ----------------
__global__ __launch_bounds__(256) void embed_kernel(
    const int* __restrict__ x, const float* __restrict__ tok,
    const float* __restrict__ pos, float* __restrict__ h)
{
    const int n = blockIdx.x, t = threadIdx.x;
    const int id = x[n];
    float4 a = *(const float4*)(tok + (size_t)id * D_ + t * 4);
    float4 p = *(const float4*)(pos + (size_t)n * D_ + t * 4);
    float4 o; o.x = a.x + p.x; o.y = a.y + p.y; o.z = a.z + p.z; o.w = a.w + p.w;
    *(float4*)(h + (size_t)n * D_ + t * 4) = o;
}

// ---------------- layernorm -> split bf16 hi/lo ----------------
__global__ __launch_bounds__(256) void ln_split_kernel(
    const float* __restrict__ x, const float* __restrict__ g,
    const float* __restrict__ b, u16* __restrict__ yhi, u16* __restrict__ ylo)
{
    __shared__ float sm[8];
    const int row = blockIdx.x, t = threadIdx.x;
    const int lane = t & 63, w = t >> 6;
    float4 v = *(const float4*)(x + (size_t)row * D_ + t * 4);
    float s = v.x + v.y + v.z + v.w;
    #pragma unroll
    for (int off = 32; off > 0; off >>= 1) s += __shfl_down(s, off);
    if (lane == 0) sm[w] = s;
    __syncthreads();
    const float mu = (sm[0] + sm[1] + sm[2] + sm[3]) * (1.0f / D_);
    float4 d; d.x = v.x - mu; d.y = v.y - mu; d.z = v.z - mu; d.w = v.w - mu;
    float s2 = d.x*d.x + d.y*d.y + d.z*d.z + d.w*d.w;
    #pragma unroll
    for (int off = 32; off > 0; off >>= 1) s2 += __shfl_down(s2, off);
    if (lane == 0) sm[4 + w] = s2;
    __syncthreads();
    const float rstd = rsqrtf((sm[4] + sm[5] + sm[6] + sm[7]) * (1.0f / D_) + 1e-5f);
    float4 gv = *(const float4*)(g + t * 4);
    float4 bv = *(const float4*)(b + t * 4);
    float o0 = d.x * rstd * gv.x + bv.x;
    float o1 = d.y * rstd * gv.y + bv.y;
    float o2 = d.z * rstd * gv.z + bv.z;
    float o3 = d.w * rstd * gv.w + bv.w;
    ushort4 hi, lo;
    split2(o0, hi.x, lo.x); split2(o1, hi.y, lo.y);
    split2(o2, hi.z, lo.z); split2(o3, hi.w, lo.w);
    *(ushort4*)(yhi + (size_t)row * D_ + t * 4) = hi;
    *(ushort4*)(ylo + (size_t)row * D_ + t * 4) = lo;
}

// ---------------- weight convert+transpose: W[K][Np]f32 -> T[Np][K] hi/lo bf16 ----
__global__ __launch_bounds__(256) void conv_t_kernel(
    const float* __restrict__ W, u16* __restrict__ Thi, u16* __restrict__ Tlo,
    int K, int Np)
{
    __shared__ float tile[32][33];
    const int t = threadIdx.x;
    const int bn = blockIdx.x * 32, bk = blockIdx.y * 32;
    const int r = t >> 3, c4 = (t & 7) << 2;
    float4 v = *(const float4*)(W + (size_t)(bk + r) * Np + bn + c4);
    tile[r][c4 + 0] = v.x; tile[r][c4 + 1] = v.y;
    tile[r][c4 + 2] = v.z; tile[r][c4 + 3] = v.w;
    __syncthreads();
    ushort4 hi, lo;
    split2(tile[c4 + 0][r], hi.x, lo.x);
    split2(tile[c4 + 1][r], hi.y, lo.y);
    split2(tile[c4 + 2][r], hi.z, lo.z);
    split2(tile[c4 + 3][r], hi.w, lo.w);
    const size_t o = (size_t)(bn + r) * K + bk + c4;
    *(ushort4*)(Thi + o) = hi;
    *(ushort4*)(Tlo + o) = lo;
}

// ---------------- tok_emb convert (no transpose): [V][D] -> hi/lo ----------------
__global__ __launch_bounds__(256) void conv_tok_kernel(
    const float* __restrict__ tok, u16* __restrict__ Thi, u16* __restrict__ Tlo)
{
    const size_t i = ((size_t)blockIdx.x * 256 + threadIdx.x) * 4;
    float4 v = *(const float4*)(tok + i);
    ushort4 hi, lo;
    split2(v.x, hi.x, lo.x); split2(v.y, hi.y, lo.y);
    split2(v.z, hi.z, lo.z); split2(v.w, hi.w, lo.w);
    *(ushort4*)(Thi + i) = hi;
    *(ushort4*)(Tlo + i) = lo;
}

// ---------------- MFMA GEMM: C[M,Np] = A[M,K] @ BT[Np,K]^T (bf16x2 split, 3 MFMA) ----
// BMODE 0: B pre-split bf16 hi/lo [Np][K].  BMODE 1: Bf fp32 [NB][K], convert in-LDS.
// EPI 0: C=f32.  EPI 1: C = acc + bias + res (f32).  EPI 2: gelu(acc+bias) -> hi/lo bf16.
// 256 thr = 4 waves (2x2 of 64x64), tile 128x128, BK=32, mfma 16x16x32 bf16.
template<int BMODE, int EPI>
__global__ __launch_bounds__(256) void gemm_mfma(
    const u16* __restrict__ Ahi, const u16* __restrict__ Alo,
    const u16* __restrict__ Bhi, const u16* __restrict__ Blo,
    const float* __restrict__ Bf,
    const float* __restrict__ bias, const float* __restrict__ res,
    float* __restrict__ Cf, u16* __restrict__ Ohi, u16* __restrict__ Olo,
    int Np, int K, int NB)
{
    __shared__ alignas(16) u16 sAh[4096], sAl[4096], sBh[4096], sBl[4096];
    __shared__ alignas(16) float sBf[BMODE == 1 ? 4096 : 4];

    const int t = threadIdx.x;
    const int lane = t & 63;
    const int wid = t >> 6, wr = wid >> 1, wc = wid & 1;
    const int bm = blockIdx.y * 128, bn = blockIdx.x * 128;

    f32x4 acc[4][4];
    #pragma unroll
    for (int i = 0; i < 4; ++i)
        #pragma unroll
        for (int j = 0; j < 4; ++j)
            acc[i][j] = (f32x4){0.f, 0.f, 0.f, 0.f};

    const int r0 = t >> 2;            // granule t -> row, k-octet
    const int ko = (t & 3) << 3;

    for (int kt = 0; kt < K; kt += 32) {
        __syncthreads();
        {
            const size_t a0 = (size_t)(bm + r0) * K + kt + ko;
            const size_t a1 = (size_t)(bm + r0 + 64) * K + kt + ko;
            gl_lds16(Ahi + a0, sAh + t * 8);
            gl_lds16(Ahi + a1, sAh + (t + 256) * 8);
            gl_lds16(Alo + a0, sAl + t * 8);
            gl_lds16(Alo + a1, sAl + (t + 256) * 8);
        }
        if constexpr (BMODE == 0) {
            const size_t b0 = (size_t)(bn + r0) * K + kt + ko;
            const size_t b1 = (size_t)(bn + r0 + 64) * K + kt + ko;
            gl_lds16(Bhi + b0, sBh + t * 8);
            gl_lds16(Bhi + b1, sBh + (t + 256) * 8);
            gl_lds16(Blo + b0, sBl + t * 8);
            gl_lds16(Blo + b1, sBl + (t + 256) * 8);
        } else {
            #pragma unroll
            for (int j = 0; j < 4; ++j) {
                const int g = t + j * 256;
                const int row = g >> 3, c4 = (g & 7) << 2;
                int br = bn + row; if (br >= NB) br = NB - 1;   // clamp OOB vocab rows
                gl_lds16(Bf + (size_t)br * K + kt + c4, sBf + g * 4);
            }
        }
        __syncthreads();   // compiler drains vmcnt(0) before s_barrier -> LDS ready
        if constexpr (BMODE == 1) {
            const int row = t >> 1, h16 = (t & 1) << 4;
            #pragma unroll
            for (int q = 0; q < 4; ++q) {
                const float* src = &sBf[row * 32 + h16 + q * 4];
                ushort4 hi, lo;
                split2(src[0], hi.x, lo.x); split2(src[1], hi.y, lo.y);
                split2(src[2], hi.z, lo.z); split2(src[3], hi.w, lo.w);
                *(ushort4*)&sBh[row * 32 + h16 + q * 4] = hi;
                *(ushort4*)&sBl[row * 32 + h16 + q * 4] = lo;
            }
            __syncthreads();
        }
        // fragments: A row = lane&15, k-octet = lane>>4 (k-contiguous b128 reads)
        bf16x8 ah[4], al[4];
        #pragma unroll
        for (int i = 0; i < 4; ++i) {
            const int off = (wr * 64 + i * 16 + (lane & 15)) * 32 + (lane >> 4) * 8;
            ah[i] = *(const bf16x8*)&sAh[off];
            al[i] = *(const bf16x8*)&sAl[off];
        }
        #pragma unroll
        for (int j = 0; j < 4; ++j) {
            const int off = (wc * 64 + j * 16 + (lane & 15)) * 32 + (lane >> 4) * 8;
            bf16x8 bh = *(const bf16x8*)&sBh[off];
            bf16x8 bl = *(const bf16x8*)&sBl[off];
            #pragma unroll
            for (int i = 0; i < 4; ++i) {
                acc[i][j] = __builtin_amdgcn_mfma_f32_16x16x32_bf16(al[i], bh, acc[i][j], 0, 0, 0);
                acc[i][j] = __builtin_amdgcn_mfma_f32_16x16x32_bf16(ah[i], bl, acc[i][j], 0, 0, 0);
                acc[i][j] = __builtin_amdgcn_mfma_f32_16x16x32_bf16(ah[i], bh, acc[i][j], 0, 0, 0);
            }
        }
    }
    // epilogue: C/D layout col = lane&15, row = (lane>>4)*4 + q  [m89-verified]
    #pragma unroll
    for (int i = 0; i < 4; ++i) {
        #pragma unroll
        for (int j = 0; j < 4; ++j) {
            const int col = bn + wc * 64 + j * 16 + (lane & 15);
            if (col >= Np) continue;
            const int row0 = bm + wr * 64 + i * 16 + ((lane >> 4) << 2);
            #pragma unroll
            for (int q = 0; q < 4; ++q) {
                const size_t idx = (size_t)(row0 + q) * Np + col;
                float v = acc[i][j][q];
                if constexpr (EPI == 2) {
                    v = gelu_exact(v + bias[col]);
                    u16 hu, lu; split2(v, hu, lu);
                    Ohi[idx] = hu; Olo[idx] = lu;
                } else {
                    if constexpr (EPI == 1) v += bias[col] + res[idx];
                    Cf[idx] = v;
                }
            }
        }
    }
}

// ---------------- flash attention (fp32, causal) -> split bf16 out ----------------
__global__ __launch_bounds__(256) void attn_kernel(const float* __restrict__ qkv,
                                                   u16* __restrict__ athi,
                                                   u16* __restrict__ atlo)
{
    constexpr int AKB = 32;
    const int hh = blockIdx.y, qb = blockIdx.x;
    const int q0 = qb * 64;
    const int t = threadIdx.x;
    const int tx = t & 15, ty = t >> 4;

    __shared__ float Qs[64][65];
    __shared__ float Ks[64][AKB + 1];
    __shared__ float Vs[AKB][64];
    __shared__ float Ps[64][AKB + 1];

    #pragma unroll
    for (int j = 0; j < 4; ++j) {
        int i = t + j * 256;
        int row = i >> 4, d0 = (i & 15) << 2;
        float4 qv = *(const float4*)(qkv + (size_t)(q0 + row) * TRI + hh * DH_ + d0);
        Qs[d0+0][row] = qv.x; Qs[d0+1][row] = qv.y;
        Qs[d0+2][row] = qv.z; Qs[d0+3][row] = qv.w;
    }

    float m[4], l[4], o[4][4];
    #pragma unroll
    for (int r = 0; r < 4; ++r) {
        m[r] = -3.0e38f; l[r] = 0.0f;
        #pragma unroll
        for (int c = 0; c < 4; ++c) o[r][c] = 0.0f;
    }

    const int nkb = 2 * (qb + 1);
    for (int kb = 0; kb < nkb; ++kb) {
        const int k0 = kb * AKB;
        __syncthreads();
        #pragma unroll
        for (int j = 0; j < 2; ++j) {
            int i = t + j * 256;
            int col = i >> 4, d0 = (i & 15) << 2;
            float4 kv = *(const float4*)(qkv + (size_t)(k0 + col) * TRI + 1024 + hh * DH_ + d0);
            Ks[d0+0][col] = kv.x; Ks[d0+1][col] = kv.y;
            Ks[d0+2][col] = kv.z; Ks[d0+3][col] = kv.w;
            float4 vv = *(const float4*)(qkv + (size_t)(k0 + col) * TRI + 2048 + hh * DH_ + d0);
            *(float4*)&Vs[col][d0] = vv;
        }
        __syncthreads();

        float s[4][2];
        #pragma unroll
        for (int r = 0; r < 4; ++r) { s[r][0] = 0.f; s[r][1] = 0.f; }
        for (int d = 0; d < 64; ++d) {
            float qa[4];
            #pragma unroll
            for (int r = 0; r < 4; ++r) qa[r] = Qs[d][ty * 4 + r];
            float kv0 = Ks[d][tx * 2 + 0];
            float kv1 = Ks[d][tx * 2 + 1];
            #pragma unroll
            for (int r = 0; r < 4; ++r) {
                s[r][0] = fmaf(qa[r], kv0, s[r][0]);
                s[r][1] = fmaf(qa[r], kv1, s[r][1]);
            }
        }
        #pragma unroll
        for (int r = 0; r < 4; ++r) {
            const int qr = q0 + ty * 4 + r;
            #pragma unroll
            for (int c = 0; c < 2; ++c) {
                const int kc = k0 + tx * 2 + c;
                s[r][c] = (kc <= qr) ? s[r][c] * 0.125f : -1e30f;
            }
        }
        #pragma unroll
        for (int r = 0; r < 4; ++r) {
            float rmax = fmaxf(s[r][0], s[r][1]);
            #pragma unroll
            for (int off = 1; off < 16; off <<= 1)
                rmax = fmaxf(rmax, __shfl_xor(rmax, off, 16));
            const float mn = fmaxf(m[r], rmax);
            const float p0 = expf(s[r][0] - mn);
            const float p1 = expf(s[r][1] - mn);
            s[r][0] = p0; s[r][1] = p1;
            float rsum = p0 + p1;
            #pragma unroll
            for (int off = 1; off < 16; off <<= 1)
                rsum += __shfl_xor(rsum, off, 16);
            const float sc = expf(m[r] - mn);
            l[r] = l[r] * sc + rsum;
            m[r] = mn;
            #pragma unroll
            for (int c = 0; c < 4; ++c) o[r][c] *= sc;
        }
        #pragma unroll
        for (int r = 0; r < 4; ++r) {
            Ps[ty * 4 + r][tx * 2 + 0] = s[r][0];
            Ps[ty * 4 + r][tx * 2 + 1] = s[r][1];
        }
        __syncthreads();
        #pragma unroll 4
        for (int j = 0; j < AKB; ++j) {
            float pv[4];
            #pragma unroll
            for (int r = 0; r < 4; ++r) pv[r] = Ps[ty * 4 + r][j];
            float4 vv = *(const float4*)&Vs[j][tx * 4];
            #pragma unroll
            for (int r = 0; r < 4; ++r) {
                o[r][0] = fmaf(pv[r], vv.x, o[r][0]);
                o[r][1] = fmaf(pv[r], vv.y, o[r][1]);
                o[r][2] = fmaf(pv[r], vv.z, o[r][2]);
                o[r][3] = fmaf(pv[r], vv.w, o[r][3]);
            }
        }
    }
    #pragma unroll
    for (int r = 0; r < 4; ++r) {
        const float inv = 1.0f / l[r];
        ushort4 hi, lo;
        split2(o[r][0] * inv, hi.x, lo.x);
        split2(o[r][1] * inv, hi.y, lo.y);
        split2(o[r][2] * inv, hi.z, lo.z);
        split2(o[r][3] * inv, hi.w, lo.w);
        const size_t idx = (size_t)(q0 + ty * 4 + r) * 1024 + hh * DH_ + tx * 4;
        *(ushort4*)(athi + idx) = hi;
        *(ushort4*)(atlo + idx) = lo;
    }
}

// ---------------- launcher ----------------
extern "C" void kernel_launch(void* const* d_in, const int* in_sizes, int n_in,
                              void* d_out, int out_size, void* d_ws, size_t ws_size,
                              hipStream_t stream)
{
    (void)in_sizes; (void)n_in; (void)out_size;
    const int*   x    = (const int*)  d_in[0];
    const float* tok  = (const float*)d_in[1];
    const float* pos  = (const float*)d_in[2];
    const float* ln1g = (const float*)d_in[3];
    const float* ln1b = (const float*)d_in[4];
    const float* wqkv = (const float*)d_in[5];
    const float* wo   = (const float*)d_in[6];
    const float* bo   = (const float*)d_in[7];
    const float* ln2g = (const float*)d_in[8];
    const float* ln2b = (const float*)d_in[9];
    const float* w1   = (const float*)d_in[10];
    const float* b1   = (const float*)d_in[11];
    const float* w2   = (const float*)d_in[12];
    const float* b2   = (const float*)d_in[13];
    const float* lnfg = (const float*)d_in[14];
    const float* lnfb = (const float*)d_in[15];
    float* out = (float*)d_out;

    // ---- workspace bump allocator (256B aligned) ----
    char* base = (char*)d_ws;
    size_t off = 0;
    auto alloc = [&](size_t bytes) -> void* {
        void* r = base + off;
        off = (off + bytes + 255) & ~(size_t)255;
        return r;
    };
    float* h    = (float*)alloc((size_t)N_ * D_ * 4);
    float* qkv  = (float*)alloc((size_t)N_ * TRI * 4);
    u16* yhi    = (u16*)alloc((size_t)N_ * D_ * 2);
    u16* ylo    = (u16*)alloc((size_t)N_ * D_ * 2);
    u16* athi   = (u16*)alloc((size_t)N_ * D_ * 2);
    u16* atlo   = (u16*)alloc((size_t)N_ * D_ * 2);
    u16* ffhi   = (u16*)alloc((size_t)N_ * FF_ * 2);
    u16* fflo   = (u16*)alloc((size_t)N_ * FF_ * 2);
    u16* wqkvTh = (u16*)alloc((size_t)2 * TRI * D_ * 2);
    u16* wqkvTl = (u16*)alloc((size_t)2 * TRI * D_ * 2);
    u16* woTh   = (u16*)alloc((size_t)2 * D_ * D_ * 2);
    u16* woTl   = (u16*)alloc((size_t)2 * D_ * D_ * 2);
    u16* w1Th   = (u16*)alloc((size_t)2 * FF_ * D_ * 2);
    u16* w1Tl   = (u16*)alloc((size_t)2 * FF_ * D_ * 2);
    u16* w2Th   = (u16*)alloc((size_t)2 * D_ * FF_ * 2);
    u16* w2Tl   = (u16*)alloc((size_t)2 * D_ * FF_ * 2);
    const size_t tokbytes = (size_t)VPAD * D_ * 2;
    const bool toksplit = (off + 2 * tokbytes) <= ws_size;   // runtime-constant -> graph-safe
    u16 *tokh = nullptr, *tokl = nullptr;
    if (toksplit) {
        tokh = (u16*)alloc(tokbytes);
        tokl = (u16*)alloc(tokbytes);
    }

    // ---- weight conversions (re-run every launch; ws is re-poisoned) ----
    for (int l = 0; l < 2; ++l) {
        conv_t_kernel<<<dim3(TRI / 32, D_ / 32), 256, 0, stream>>>(
            wqkv + (size_t)l * D_ * TRI, wqkvTh + (size_t)l * TRI * D_,
            wqkvTl + (size_t)l * TRI * D_, D_, TRI);
        conv_t_kernel<<<dim3(D_ / 32, D_ / 32), 256, 0, stream>>>(
            wo + (size_t)l * D_ * D_, woTh + (size_t)l * D_ * D_,
            woTl + (size_t)l * D_ * D_, D_, D_);
        conv_t_kernel<<<dim3(FF_ / 32, D_ / 32), 256, 0, stream>>>(
            w1 + (size_t)l * D_ * FF_, w1Th + (size_t)l * FF_ * D_,
            w1Tl + (size_t)l * FF_ * D_, D_, FF_);
        conv_t_kernel<<<dim3(D_ / 32, FF_ / 32), 256, 0, stream>>>(
            w2 + (size_t)l * FF_ * D_, w2Th + (size_t)l * D_ * FF_,
            w2Tl + (size_t)l * D_ * FF_, FF_, D_);
    }
    if (toksplit)
        conv_tok_kernel<<<V_, 256, 0, stream>>>(tok, tokh, tokl);

    embed_kernel<<<N_, 256, 0, stream>>>(x, tok, pos, h);

    for (int l = 0; l < 2; ++l) {
        ln_split_kernel<<<N_, 256, 0, stream>>>(h, ln1g + l * D_, ln1b + l * D_, yhi, ylo);
        gemm_mfma<0, 0><<<dim3(TRI / 128, N_ / 128), 256, 0, stream>>>(
            yhi, ylo, wqkvTh + (size_t)l * TRI * D_, wqkvTl + (size_t)l * TRI * D_,
            nullptr, nullptr, nullptr, qkv, nullptr, nullptr, TRI, D_, 0);
        attn_kernel<<<dim3(N_ / 64, H_), 256, 0, stream>>>(qkv, athi, atlo);
        gemm_mfma<0, 1><<<dim3(D_ / 128, N_ / 128), 256, 0, stream>>>(
            athi, atlo, woTh + (size_t)l * D_ * D_, woTl + (size_t)l * D_ * D_,
            nullptr, bo + l * D_, h, h, nullptr, nullptr, D_, D_, 0);
        ln_split_kernel<<<N_, 256, 0, stream>>>(h, ln2g + l * D_, ln2b + l * D_, yhi, ylo);
        gemm_mfma<0, 2><<<dim3(FF_ / 128, N_ / 128), 256, 0, stream>>>(
            yhi, ylo, w1Th + (size_t)l * FF_ * D_, w1Tl + (size_t)l * FF_ * D_,
            nullptr, b1 + l * FF_, nullptr, nullptr, ffhi, fflo, FF_, D_, 0);
        gemm_mfma<0, 1><<<dim3(D_ / 128, N_ / 128), 256, 0, stream>>>(
            ffhi, fflo, w2Th + (size_t)l * D_ * FF_, w2Tl + (size_t)l * D_ * FF_,
            nullptr, b2 + l * D_, h, h, nullptr, nullptr, D_, FF_, 0);
    }
    ln_split_kernel<<<N_, 256, 0, stream>>>(h, lnfg, lnfb, yhi, ylo);

    if (toksplit) {
        gemm_mfma<0, 0><<<dim3(VPAD / 128, N_ / 128), 256, 0, stream>>>(
            yhi, ylo, tokh, tokl, nullptr, nullptr, nullptr, out,
            nullptr, nullptr, V_, D_, 0);
    } else {
        gemm_mfma<1, 0><<<dim3(VPAD / 128, N_ / 128), 256, 0, stream>>>(
            yhi, ylo, nullptr, nullptr, tok, nullptr, nullptr, out,
            nullptr, nullptr, V_, D_, V_);
    }
}